// Round 9
// baseline (187.876 us; speedup 1.0000x reference)
//
#include <hip/hip_runtime.h>
#include <hip/hip_bf16.h>

#define B_ 8
#define S_ 2048
#define E_ 1024
#define D_ 64
#define VT_STRIDE 2112   // 2048 + 64: breaks 4KB channel camping

typedef short short8 __attribute__((ext_vector_type(8)));
typedef short short4v __attribute__((ext_vector_type(4)));
typedef float floatx4 __attribute__((ext_vector_type(4)));

static __device__ __forceinline__ short bf16_bits(float f) {
    __hip_bfloat16 h = __float2bfloat16(f);
    return *reinterpret_cast<short*>(&h);
}
static __device__ __forceinline__ float bits_to_f(short s) {
    __hip_bfloat16 h = *reinterpret_cast<__hip_bfloat16*>(&s);
    return __bfloat162float(h);
}
static __device__ __forceinline__ void split8(const float* __restrict__ p,
                                              short8& hi, short8& lo) {
    #pragma unroll
    for (int j = 0; j < 8; j++) {
        float f = p[j];
        short h = bf16_bits(f);
        hi[j] = h;
        lo[j] = bf16_bits(f - bits_to_f(h));
    }
}
static __device__ __forceinline__ void split8v(const float v[8],
                                               short8& hi, short8& lo) {
    #pragma unroll
    for (int j = 0; j < 8; j++) {
        float f = v[j];
        short h = bf16_bits(f);
        hi[j] = h;
        lo[j] = bf16_bits(f - bits_to_f(h));
    }
}
static __device__ __forceinline__ void dma16(const void* src, void* lds_dst) {
    __builtin_amdgcn_global_load_lds(
        (const __attribute__((address_space(1))) unsigned int*)src,
        (__attribute__((address_space(3))) unsigned int*)lds_dst, 16, 0, 0);
}

// ---------------- prep: blocks 0..95 = W pre-pack, 96..159 = mask prep.
// New Wpk layout (short8 units): ((e0c*3+m)*2+h)*256 + nb*64 + quad*16 + l16
// -> per-e0c 24KB chunk is DMA-linear, reads are lane-contiguous b128.
__global__ __launch_bounds__(256) void prep_kernel(
    const float* __restrict__ Wq, const float* __restrict__ Wk,
    const float* __restrict__ Wv, short8* __restrict__ Wpk8,
    const void* __restrict__ mask_raw, float* __restrict__ maskf)
{
    __shared__ unsigned int red[256];
    if (blockIdx.x < 96) {
        const int t = blockIdx.x * 256 + threadIdx.x;       // 24576 total
        const int l16  = t & 15;
        const int quad = (t >> 4) & 3;
        const int nb   = (t >> 6) & 3;
        const int m    = (t >> 8) % 3;
        const int e0c  = (t >> 8) / 3;                      // 0..31
        const float* W = (m == 0) ? Wq : ((m == 1) ? Wk : Wv);
        short8 hi, lo;
        split8(W + (size_t)(nb * 16 + l16) * E_ + e0c * 32 + quad * 8, hi, lo);
        const size_t pos = (size_t)((e0c * 3 + m) * 2) * 256 + nb * 64 + quad * 16 + l16;
        Wpk8[pos]       = hi;
        Wpk8[pos + 256] = lo;
    } else {
        const unsigned int* w = (const unsigned int*)mask_raw;
        unsigned int local = 0;
        for (int i = threadIdx.x; i < 4096; i += 256) local |= w[i];
        red[threadIdx.x] = local;
        __syncthreads();
        for (int s = 128; s > 0; s >>= 1) {
            if (threadIdx.x < s) red[threadIdx.x] |= red[threadIdx.x + s];
            __syncthreads();
        }
        const unsigned int ov = red[0];
        const bool is_u8 = (ov > 1u) && ((ov >> 24) <= 1u);
        const int i = (blockIdx.x - 96) * 256 + threadIdx.x;  // 64 blocks
        int v;
        if (ov == 0u)      v = 0;
        else if (is_u8)    v = (int)((const unsigned char*)mask_raw)[i];
        else               v = (((const unsigned int*)mask_raw)[i] != 0u);
        maskf[i] = v ? -1e30f : 0.0f;
    }
}

// ---------------- QKV: 32 rows/block, 512 thr (8 waves = 4 nb x 2 rt),
// grid 512 -> 16 waves/CU. x AND W staged via global_load_lds double buffer;
// loop body has zero global loads (compiler cannot sink DMA).
__global__ __launch_bounds__(512, 4) void qkv_kernel(
    const float* __restrict__ x, const short8* __restrict__ Wpk8,
    const float* __restrict__ bq, const float* __restrict__ bk,
    const float* __restrict__ bv,
    short* __restrict__ Qhi, short* __restrict__ Qlo,
    short* __restrict__ Khi, short* __restrict__ Vt)
{
    __shared__ alignas(16) float  xs[2][1024];    // 2 x 4KB  [row*32 + chunk*4]
    __shared__ alignas(16) short8 wt[2][1536];    // 2 x 24KB [(m*2+h)*256 + nb*64 + lane]
    const int tid  = threadIdx.x;
    const int wave = tid >> 6;
    const int nb   = wave & 3;
    const int rt   = wave >> 2;
    const int lane = tid & 63;
    const int l16  = lane & 15;
    const int quad = lane >> 4;
    const int row0 = blockIdx.x * 32;

    // x DMA mapping (waves 0-3): thread t -> row t>>3, stored chunk t&7 holds
    // source chunk (t&7)^(row&7)  (read-side swizzle inverse)
    const float* xsrc = x + (size_t)(row0 + (tid >> 3)) * E_ +
                        (((tid & 7) ^ ((tid >> 3) & 7)) * 4);

    floatx4 acc[3];
    #pragma unroll
    for (int m = 0; m < 3; m++) acc[m] = (floatx4){0.f,0.f,0.f,0.f};

    // prime buffer 0 (e0c = 0)
    if (tid < 256) dma16(xsrc, &xs[0][tid * 4]);
    #pragma unroll
    for (int i = 0; i < 3; i++)
        dma16(Wpk8 + (size_t)i * 512 + tid, &wt[0][i * 512 + tid]);

    int buf = 0;
    for (int e0c = 0; e0c < 32; ++e0c) {
        __syncthreads();   // drains this buf's DMA; prior reads of other buf done
        if (e0c + 1 < 32) {
            if (tid < 256) dma16(xsrc + (e0c + 1) * 32, &xs[buf ^ 1][tid * 4]);
            #pragma unroll
            for (int i = 0; i < 3; i++)
                dma16(Wpk8 + (size_t)(e0c + 1) * 1536 + i * 512 + tid,
                      &wt[buf ^ 1][i * 512 + tid]);
        }

        const int rr = rt * 16 + l16;
        const int rx = rr & 7;
        const float* xr = &xs[buf][rr * 32];
        float4 a0 = *reinterpret_cast<const float4*>(xr + (((2 * quad)     ^ rx) * 4));
        float4 a1 = *reinterpret_cast<const float4*>(xr + (((2 * quad + 1) ^ rx) * 4));
        float av[8] = {a0.x, a0.y, a0.z, a0.w, a1.x, a1.y, a1.z, a1.w};
        short8 ah, al;
        split8v(av, ah, al);

        #pragma unroll
        for (int m = 0; m < 3; m++) {
            short8 wh = wt[buf][(m * 2 + 0) * 256 + nb * 64 + lane];
            short8 wl = wt[buf][(m * 2 + 1) * 256 + nb * 64 + lane];
            acc[m] = __builtin_amdgcn_mfma_f32_16x16x32_bf16(al, wh, acc[m], 0, 0, 0);
            acc[m] = __builtin_amdgcn_mfma_f32_16x16x32_bf16(ah, wl, acc[m], 0, 0, 0);
            acc[m] = __builtin_amdgcn_mfma_f32_16x16x32_bf16(ah, wh, acc[m], 0, 0, 0);
        }
        buf ^= 1;
    }

    // epilogue: C rows = row0 + rt*16 + quad*4 + r, col d = nb*16 + l16
    const int d = nb * 16 + l16;
    const float bqv = bq[d];
    const float bkv = bk[d];
    const float bvv = bv[d];
    const int bch = row0 >> 11;
    const int rowbase = row0 + rt * 16 + quad * 4;
    short4v vpk;
    #pragma unroll
    for (int r = 0; r < 4; r++) {
        const size_t row = (size_t)(rowbase + r);
        const float q = (acc[0][r] + bqv) * 0.125f;
        const short qhv = bf16_bits(q);
        Qhi[row * 64 + d] = qhv;
        Qlo[row * 64 + d] = bf16_bits(q - bits_to_f(qhv));
        Khi[row * 64 + d] = bf16_bits(acc[1][r] + bkv);
        vpk[r] = bf16_bits(acc[2][r] + bvv);
    }
    *reinterpret_cast<short4v*>(Vt + ((size_t)(bch * 64 + d)) * VT_STRIDE +
                                (rowbase & 2047)) = vpk;
}

// ---------------- Flash attention: 64 q/block (4 waves x 16 q), no key split,
// grid 256. K/V tiles DMA-staged (XOR-swizzled), double-buffered, shared by
// all waves. Mask register-prefetched one tile ahead (barrier completes it).
__global__ __launch_bounds__(256, 1) void attn_kernel(
    const short* __restrict__ Qhi, const short* __restrict__ Qlo,
    const short* __restrict__ Khi, const short* __restrict__ Vt,
    const float* __restrict__ maskf, float* __restrict__ out)
{
    __shared__ alignas(16) short8 kts[2][512];   // 2 x 8KB  [key*8 + swz-chunk]
    __shared__ alignas(16) short8 vts[2][512];   // 2 x 8KB  [d*8 + swz-chunk]
    __shared__ short PlT[4][16][72];             // per-wave P^T round-trip

    const int tid  = threadIdx.x;
    const int wave = tid >> 6;          // q sub-tile 0..3
    const int lane = tid & 63;
    const int l16  = lane & 15;
    const int quad = lane >> 4;
    const int b    = blockIdx.x >> 5;
    const int qt   = blockIdx.x & 31;
    const size_t qbase  = (size_t)b * S_ + qt * 64 + wave * 16;
    const size_t kplane = (size_t)b * S_;
    const short* Vb = Vt + (size_t)b * 64 * VT_STRIDE;

    // Q fragments (B-operand: lane=query l16, k=d)
    short8 qh[2], ql[2];
    #pragma unroll
    for (int dc = 0; dc < 2; dc++) {
        qh[dc] = *reinterpret_cast<const short8*>(Qhi + (qbase + l16) * 64 + dc * 32 + quad * 8);
        ql[dc] = *reinterpret_cast<const short8*>(Qlo + (qbase + l16) * 64 + dc * 32 + quad * 8);
    }

    float m = -1e30f, l = 0.f;
    floatx4 O[4];
    #pragma unroll
    for (int ob = 0; ob < 4; ob++) O[ob] = (floatx4){0.f,0.f,0.f,0.f};

    // prime tile 0: K/V DMA (chunk c: key/d = c>>3, stored cs holds src cs^(r&7))
    #pragma unroll
    for (int i = 0; i < 2; i++) {
        const int c = i * 256 + tid;
        const int r = c >> 3, cs = c & 7;
        dma16(Khi + (kplane + r) * 64 + ((cs ^ (r & 7)) * 8), &kts[0][c]);
        dma16(Vb + (size_t)r * VT_STRIDE + ((cs ^ (r & 7)) * 8), &vts[0][c]);
    }
    float4 mk4[4];
    #pragma unroll
    for (int kb = 0; kb < 4; kb++)
        mk4[kb] = *reinterpret_cast<const float4*>(maskf + kplane + kb * 16 + quad * 4);

    int buf = 0;
    for (int t = 0; t < 32; ++t) {
        __syncthreads();   // vmcnt(0) drain: this buf's DMA + mask prefetch done
        if (t + 1 < 32) {
            const int ktn = (t + 1) * 64;
            #pragma unroll
            for (int i = 0; i < 2; i++) {
                const int c = i * 256 + tid;
                const int r = c >> 3, cs = c & 7;
                dma16(Khi + (kplane + ktn + r) * 64 + ((cs ^ (r & 7)) * 8), &kts[buf ^ 1][c]);
                dma16(Vb + (size_t)r * VT_STRIDE + ktn + ((cs ^ (r & 7)) * 8), &vts[buf ^ 1][c]);
            }
        }

        // S^T = K . Q^T  (rows=keys quad*4+r, cols=queries l16)
        floatx4 sc[4];
        #pragma unroll
        for (int kb = 0; kb < 4; kb++) {
            floatx4 a = (floatx4){0.f,0.f,0.f,0.f};
            #pragma unroll
            for (int kc = 0; kc < 2; kc++) {
                const int key = kb * 16 + l16;
                short8 kf = kts[buf][key * 8 + ((kc * 4 + quad) ^ (key & 7))];
                a = __builtin_amdgcn_mfma_f32_16x16x32_bf16(kf, qh[kc], a, 0, 0, 0);
                a = __builtin_amdgcn_mfma_f32_16x16x32_bf16(kf, ql[kc], a, 0, 0, 0);
            }
            sc[kb] = a;
        }
        #pragma unroll
        for (int kb = 0; kb < 4; kb++) {
            const float* mkp = reinterpret_cast<const float*>(&mk4[kb]);
            #pragma unroll
            for (int r = 0; r < 4; r++) sc[kb][r] += mkp[r];
        }

        // online softmax for query l16: in-lane tree + 2 cross-quad shuffles
        float mx = -1e30f;
        #pragma unroll
        for (int kb = 0; kb < 4; kb++)
            #pragma unroll
            for (int r = 0; r < 4; r++) mx = fmaxf(mx, sc[kb][r]);
        mx = fmaxf(mx, __shfl_xor(mx, 16, 64));
        mx = fmaxf(mx, __shfl_xor(mx, 32, 64));
        const float mnew  = fmaxf(fmaxf(m, mx), -1e29f);
        const float alpha = __expf(m - mnew);
        float ps = 0.f;
        #pragma unroll
        for (int kb = 0; kb < 4; kb++)
            #pragma unroll
            for (int r = 0; r < 4; r++) {
                const float pe = __expf(sc[kb][r] - mnew);
                sc[kb][r] = pe;
                ps += pe;
            }
        ps += __shfl_xor(ps, 16, 64);
        ps += __shfl_xor(ps, 32, 64);
        l = l * alpha + ps;
        m = mnew;
        #pragma unroll
        for (int ob = 0; ob < 4; ob++) O[ob] *= alpha;

        // P^T -> B-operand layout via per-wave LDS (same-wave ds ordering)
        #pragma unroll
        for (int kb = 0; kb < 4; kb++)
            #pragma unroll
            for (int r = 0; r < 4; r++)
                PlT[wave][l16][kb * 16 + quad * 4 + r] = bf16_bits(sc[kb][r]);
        short8 pf[2];
        #pragma unroll
        for (int kc = 0; kc < 2; kc++)
            pf[kc] = *reinterpret_cast<const short8*>(&PlT[wave][l16][kc * 32 + quad * 8]);

        #pragma unroll
        for (int ob = 0; ob < 4; ob++)
            #pragma unroll
            for (int kc = 0; kc < 2; kc++) {
                const int dd = ob * 16 + l16;
                short8 vf = vts[buf][dd * 8 + ((kc * 4 + quad) ^ (dd & 7))];
                O[ob] = __builtin_amdgcn_mfma_f32_16x16x32_bf16(vf, pf[kc], O[ob], 0, 0, 0);
            }

        // mask register-prefetch for next tile (issued before next barrier)
        if (t + 1 < 32) {
            const int ktn = (t + 1) * 64;
            #pragma unroll
            for (int kb = 0; kb < 4; kb++)
                mk4[kb] = *reinterpret_cast<const float4*>(
                    maskf + kplane + ktn + kb * 16 + quad * 4);
        }
        buf ^= 1;
    }

    // epilogue (no merge): O^T rows d = ob*16+quad*4+r, col q = l16
    #pragma unroll
    for (int ob = 0; ob < 4; ob++)
        #pragma unroll
        for (int r = 0; r < 4; r++)
            out[(qbase + l16) * 64 + ob * 16 + quad * 4 + r] = O[ob][r] / l;
}

extern "C" void kernel_launch(void* const* d_in, const int* in_sizes, int n_in,
                              void* d_out, int out_size, void* d_ws, size_t ws_size,
                              hipStream_t stream) {
    const float* x  = (const float*)d_in[0];
    const float* Wq = (const float*)d_in[1];
    const float* bq = (const float*)d_in[2];
    const float* Wk = (const float*)d_in[3];
    const float* bk = (const float*)d_in[4];
    const float* Wv = (const float*)d_in[5];
    const float* bv = (const float*)d_in[6];
    const void* mask = d_in[7];

    char* ws = (char*)d_ws;
    const size_t PLANE = (size_t)B_ * S_ * D_;           // 1M shorts = 2MB
    short* Wpk = (short*)ws;                              // 768 KB
    short* Qhi = (short*)(ws + 768 * 1024);
    short* Qlo = Qhi + PLANE;
    short* Khi = Qlo + PLANE;
    short* Vt  = Khi + PLANE;                             // 512*2112 shorts
    float* maskf = (float*)(Vt + (size_t)512 * VT_STRIDE);

    prep_kernel<<<160, 256, 0, stream>>>(Wq, Wk, Wv, (short8*)Wpk, mask, maskf);
    qkv_kernel<<<512, 512, 0, stream>>>(x, (const short8*)Wpk, bq, bk, bv,
                                        Qhi, Qlo, Khi, Vt);
    attn_kernel<<<256, 256, 0, stream>>>(Qhi, Qlo, Khi, Vt, maskf,
                                         (float*)d_out);
}

// Round 10
// 168.094 us; speedup vs baseline: 1.1177x; 1.1177x over previous
//
#include <hip/hip_runtime.h>
#include <hip/hip_bf16.h>

#define B_ 8
#define S_ 2048
#define E_ 1024
#define D_ 64
#define VT_STRIDE 2112   // 2048 + 64: breaks 4KB channel camping

typedef short short8 __attribute__((ext_vector_type(8)));
typedef short short4v __attribute__((ext_vector_type(4)));
typedef float floatx4 __attribute__((ext_vector_type(4)));

static __device__ __forceinline__ short bf16_bits(float f) {
    __hip_bfloat16 h = __float2bfloat16(f);
    return *reinterpret_cast<short*>(&h);
}
static __device__ __forceinline__ float bits_to_f(short s) {
    __hip_bfloat16 h = *reinterpret_cast<__hip_bfloat16*>(&s);
    return __bfloat162float(h);
}
static __device__ __forceinline__ void split8(const float* __restrict__ p,
                                              short8& hi, short8& lo) {
    #pragma unroll
    for (int j = 0; j < 8; j++) {
        float f = p[j];
        short h = bf16_bits(f);
        hi[j] = h;
        lo[j] = bf16_bits(f - bits_to_f(h));
    }
}
static __device__ __forceinline__ void split8v(const float v[8],
                                               short8& hi, short8& lo) {
    #pragma unroll
    for (int j = 0; j < 8; j++) {
        float f = v[j];
        short h = bf16_bits(f);
        hi[j] = h;
        lo[j] = bf16_bits(f - bits_to_f(h));
    }
}
static __device__ __forceinline__ void dma16(const void* src, void* lds_dst) {
    __builtin_amdgcn_global_load_lds(
        (const __attribute__((address_space(1))) unsigned int*)src,
        (__attribute__((address_space(3))) unsigned int*)lds_dst, 16, 0, 0);
}

// ---------------- prep: blocks 0..95 = W pre-pack, 96..159 = mask prep.
__global__ __launch_bounds__(256) void prep_kernel(
    const float* __restrict__ Wq, const float* __restrict__ Wk,
    const float* __restrict__ Wv, short8* __restrict__ Wpk8,
    const void* __restrict__ mask_raw, float* __restrict__ maskf)
{
    __shared__ unsigned int red[256];
    if (blockIdx.x < 96) {
        const int t = blockIdx.x * 256 + threadIdx.x;       // 24576 total
        const int l16  = t & 15;
        const int quad = (t >> 4) & 3;
        const int nb   = (t >> 6) & 3;
        const int m    = (t >> 8) % 3;
        const int e0c  = (t >> 8) / 3;                      // 0..31
        const float* W = (m == 0) ? Wq : ((m == 1) ? Wk : Wv);
        short8 hi, lo;
        split8(W + (size_t)(nb * 16 + l16) * E_ + e0c * 32 + quad * 8, hi, lo);
        const size_t pos = (size_t)((e0c * 3 + m) * 2) * 256 + nb * 64 + quad * 16 + l16;
        Wpk8[pos]       = hi;
        Wpk8[pos + 256] = lo;
    } else {
        const unsigned int* w = (const unsigned int*)mask_raw;
        unsigned int local = 0;
        for (int i = threadIdx.x; i < 4096; i += 256) local |= w[i];
        red[threadIdx.x] = local;
        __syncthreads();
        for (int s = 128; s > 0; s >>= 1) {
            if (threadIdx.x < s) red[threadIdx.x] |= red[threadIdx.x + s];
            __syncthreads();
        }
        const unsigned int ov = red[0];
        const bool is_u8 = (ov > 1u) && ((ov >> 24) <= 1u);
        const int i = (blockIdx.x - 96) * 256 + threadIdx.x;  // 64 blocks
        int v;
        if (ov == 0u)      v = 0;
        else if (is_u8)    v = (int)((const unsigned char*)mask_raw)[i];
        else               v = (((const unsigned int*)mask_raw)[i] != 0u);
        maskf[i] = v ? -1e30f : 0.0f;
    }
}

// ---------------- QKV (unchanged from round 9): 32 rows/block, 512 thr,
// grid 512. x AND W staged via global_load_lds double buffer.
__global__ __launch_bounds__(512, 4) void qkv_kernel(
    const float* __restrict__ x, const short8* __restrict__ Wpk8,
    const float* __restrict__ bq, const float* __restrict__ bk,
    const float* __restrict__ bv,
    short* __restrict__ Qhi, short* __restrict__ Qlo,
    short* __restrict__ Khi, short* __restrict__ Vt)
{
    __shared__ alignas(16) float  xs[2][1024];    // 2 x 4KB
    __shared__ alignas(16) short8 wt[2][1536];    // 2 x 24KB
    const int tid  = threadIdx.x;
    const int wave = tid >> 6;
    const int nb   = wave & 3;
    const int rt   = wave >> 2;
    const int lane = tid & 63;
    const int l16  = lane & 15;
    const int quad = lane >> 4;
    const int row0 = blockIdx.x * 32;

    const float* xsrc = x + (size_t)(row0 + (tid >> 3)) * E_ +
                        (((tid & 7) ^ ((tid >> 3) & 7)) * 4);

    floatx4 acc[3];
    #pragma unroll
    for (int m = 0; m < 3; m++) acc[m] = (floatx4){0.f,0.f,0.f,0.f};

    if (tid < 256) dma16(xsrc, &xs[0][tid * 4]);
    #pragma unroll
    for (int i = 0; i < 3; i++)
        dma16(Wpk8 + (size_t)i * 512 + tid, &wt[0][i * 512 + tid]);

    int buf = 0;
    for (int e0c = 0; e0c < 32; ++e0c) {
        __syncthreads();
        if (e0c + 1 < 32) {
            if (tid < 256) dma16(xsrc + (e0c + 1) * 32, &xs[buf ^ 1][tid * 4]);
            #pragma unroll
            for (int i = 0; i < 3; i++)
                dma16(Wpk8 + (size_t)(e0c + 1) * 1536 + i * 512 + tid,
                      &wt[buf ^ 1][i * 512 + tid]);
        }

        const int rr = rt * 16 + l16;
        const int rx = rr & 7;
        const float* xr = &xs[buf][rr * 32];
        float4 a0 = *reinterpret_cast<const float4*>(xr + (((2 * quad)     ^ rx) * 4));
        float4 a1 = *reinterpret_cast<const float4*>(xr + (((2 * quad + 1) ^ rx) * 4));
        float av[8] = {a0.x, a0.y, a0.z, a0.w, a1.x, a1.y, a1.z, a1.w};
        short8 ah, al;
        split8v(av, ah, al);

        #pragma unroll
        for (int m = 0; m < 3; m++) {
            short8 wh = wt[buf][(m * 2 + 0) * 256 + nb * 64 + lane];
            short8 wl = wt[buf][(m * 2 + 1) * 256 + nb * 64 + lane];
            acc[m] = __builtin_amdgcn_mfma_f32_16x16x32_bf16(al, wh, acc[m], 0, 0, 0);
            acc[m] = __builtin_amdgcn_mfma_f32_16x16x32_bf16(ah, wl, acc[m], 0, 0, 0);
            acc[m] = __builtin_amdgcn_mfma_f32_16x16x32_bf16(ah, wh, acc[m], 0, 0, 0);
        }
        buf ^= 1;
    }

    const int d = nb * 16 + l16;
    const float bqv = bq[d];
    const float bkv = bk[d];
    const float bvv = bv[d];
    const int bch = row0 >> 11;
    const int rowbase = row0 + rt * 16 + quad * 4;
    short4v vpk;
    #pragma unroll
    for (int r = 0; r < 4; r++) {
        const size_t row = (size_t)(rowbase + r);
        const float q = (acc[0][r] + bqv) * 0.125f;
        const short qhv = bf16_bits(q);
        Qhi[row * 64 + d] = qhv;
        Qlo[row * 64 + d] = bf16_bits(q - bits_to_f(qhv));
        Khi[row * 64 + d] = bf16_bits(acc[1][r] + bkv);
        vpk[r] = bf16_bits(acc[2][r] + bvv);
    }
    *reinterpret_cast<short4v*>(Vt + ((size_t)(bch * 64 + d)) * VT_STRIDE +
                                (rowbase & 2047)) = vpk;
}

// ---------------- Flash attention: 32 q/block, grid 512 (2 blocks/CU).
// 4 waves = (q-subtile 0/1) x (key parity even/odd). Each barrier round
// stages a PAIR of K/V tiles (4-buffer sets) shared by all waves; in-block
// LSE merge of the two key-parity partials at the end.
union alignas(16) AttnLds {
    struct { short8 kts[4][512]; short8 vts[4][512]; } st;  // 64KB
    struct {
        float Osh[4][16][65];           // [wave][q-in-sub][d]
        float msh[4][16], lsh[4][16];
    } mg;
};

__global__ __launch_bounds__(256, 2) void attn_kernel(
    const short* __restrict__ Qhi, const short* __restrict__ Qlo,
    const short* __restrict__ Khi, const short* __restrict__ Vt,
    const float* __restrict__ maskf, float* __restrict__ out)
{
    __shared__ AttnLds lds;
    __shared__ short PlT[4][16][72];    // per-wave P^T round-trip (outside union)

    const int tid  = threadIdx.x;
    const int wave = tid >> 6;
    const int qsub = wave & 1;          // q subtile 0/1
    const int par  = wave >> 1;         // key-tile parity 0/1
    const int lane = tid & 63;
    const int l16  = lane & 15;
    const int quad = lane >> 4;
    const int b    = blockIdx.x >> 6;
    const int qt   = blockIdx.x & 63;   // 64 tiles of 32 q
    const size_t qbase  = (size_t)b * S_ + qt * 32 + qsub * 16;
    const size_t kplane = (size_t)b * S_;
    const short* Vb = Vt + (size_t)b * 64 * VT_STRIDE;

    // Q fragments (B-operand: lane=query l16, k=d)
    short8 qh[2], ql[2];
    #pragma unroll
    for (int dc = 0; dc < 2; dc++) {
        qh[dc] = *reinterpret_cast<const short8*>(Qhi + (qbase + l16) * 64 + dc * 32 + quad * 8);
        ql[dc] = *reinterpret_cast<const short8*>(Qlo + (qbase + l16) * 64 + dc * 32 + quad * 8);
    }

    float m = -1e30f, l = 0.f;
    floatx4 O[4];
    #pragma unroll
    for (int ob = 0; ob < 4; ob++) O[ob] = (floatx4){0.f,0.f,0.f,0.f};

    // DMA helper pattern: chunk c of a tile: row r=c>>3, stored chunk cs=c&7
    // holds source chunk cs^(r&7). Per round stage tile pair {2R, 2R+1}.
    // prime round 0 pair into set 0 (bufs 0 = even, 1 = odd)
    #pragma unroll
    for (int p = 0; p < 2; p++) {       // tile 0(p=0), 1(p=1)
        #pragma unroll
        for (int i = 0; i < 2; i++) {
            const int c = i * 256 + tid;
            const int r = c >> 3, cs = c & 7;
            dma16(Khi + (kplane + p * 64 + r) * 64 + ((cs ^ (r & 7)) * 8),
                  &lds.st.kts[p][c]);
            dma16(Vb + (size_t)r * VT_STRIDE + p * 64 + ((cs ^ (r & 7)) * 8),
                  &lds.st.vts[p][c]);
        }
    }
    // mask prefetch for this wave's first tile (tile = par)
    float4 mk4[4];
    #pragma unroll
    for (int kb = 0; kb < 4; kb++)
        mk4[kb] = *reinterpret_cast<const float4*>(
            maskf + kplane + par * 64 + kb * 16 + quad * 4);

    for (int R = 0; R < 16; ++R) {
        __syncthreads();   // drains the pair staged for this round (+ mask)
        const int set = R & 1;
        if (R + 1 < 16) {
            const int nset = set ^ 1;
            const int kt2 = (R + 1) * 128;   // first key of next pair
            #pragma unroll
            for (int p = 0; p < 2; p++) {
                #pragma unroll
                for (int i = 0; i < 2; i++) {
                    const int c = i * 256 + tid;
                    const int r = c >> 3, cs = c & 7;
                    dma16(Khi + (kplane + kt2 + p * 64 + r) * 64 + ((cs ^ (r & 7)) * 8),
                          &lds.st.kts[nset * 2 + p][c]);
                    dma16(Vb + (size_t)r * VT_STRIDE + kt2 + p * 64 + ((cs ^ (r & 7)) * 8),
                          &lds.st.vts[nset * 2 + p][c]);
                }
            }
        }
        const int buf = set * 2 + par;

        // S^T = K . Q^T  (rows=keys quad*4+r, cols=queries l16)
        floatx4 sc[4];
        #pragma unroll
        for (int kb = 0; kb < 4; kb++) {
            floatx4 a = (floatx4){0.f,0.f,0.f,0.f};
            #pragma unroll
            for (int kc = 0; kc < 2; kc++) {
                const int key = kb * 16 + l16;
                short8 kf = lds.st.kts[buf][key * 8 + ((kc * 4 + quad) ^ (key & 7))];
                a = __builtin_amdgcn_mfma_f32_16x16x32_bf16(kf, qh[kc], a, 0, 0, 0);
                a = __builtin_amdgcn_mfma_f32_16x16x32_bf16(kf, ql[kc], a, 0, 0, 0);
            }
            sc[kb] = a;
        }
        #pragma unroll
        for (int kb = 0; kb < 4; kb++) {
            const float* mkp = reinterpret_cast<const float*>(&mk4[kb]);
            #pragma unroll
            for (int r = 0; r < 4; r++) sc[kb][r] += mkp[r];
        }

        // mask prefetch for next round's tile (issued before softmax)
        if (R + 1 < 16) {
            const int ktn = (R + 1) * 128 + par * 64;
            #pragma unroll
            for (int kb = 0; kb < 4; kb++)
                mk4[kb] = *reinterpret_cast<const float4*>(
                    maskf + kplane + ktn + kb * 16 + quad * 4);
        }

        // online softmax (query l16): in-lane tree + 2 cross-quad shuffles
        float mx = -1e30f;
        #pragma unroll
        for (int kb = 0; kb < 4; kb++)
            #pragma unroll
            for (int r = 0; r < 4; r++) mx = fmaxf(mx, sc[kb][r]);
        mx = fmaxf(mx, __shfl_xor(mx, 16, 64));
        mx = fmaxf(mx, __shfl_xor(mx, 32, 64));
        const float mnew  = fmaxf(fmaxf(m, mx), -1e29f);
        const float alpha = __expf(m - mnew);
        float ps = 0.f;
        #pragma unroll
        for (int kb = 0; kb < 4; kb++)
            #pragma unroll
            for (int r = 0; r < 4; r++) {
                const float pe = __expf(sc[kb][r] - mnew);
                sc[kb][r] = pe;
                ps += pe;
            }
        ps += __shfl_xor(ps, 16, 64);
        ps += __shfl_xor(ps, 32, 64);
        l = l * alpha + ps;
        m = mnew;
        #pragma unroll
        for (int ob = 0; ob < 4; ob++) O[ob] *= alpha;

        // P^T -> B-operand layout via per-wave LDS
        #pragma unroll
        for (int kb = 0; kb < 4; kb++)
            #pragma unroll
            for (int r = 0; r < 4; r++)
                PlT[wave][l16][kb * 16 + quad * 4 + r] = bf16_bits(sc[kb][r]);
        short8 pf[2];
        #pragma unroll
        for (int kc = 0; kc < 2; kc++)
            pf[kc] = *reinterpret_cast<const short8*>(&PlT[wave][l16][kc * 32 + quad * 8]);

        #pragma unroll
        for (int ob = 0; ob < 4; ob++)
            #pragma unroll
            for (int kc = 0; kc < 2; kc++) {
                const int dd = ob * 16 + l16;
                short8 vf = lds.st.vts[buf][dd * 8 + ((kc * 4 + quad) ^ (dd & 7))];
                O[ob] = __builtin_amdgcn_mfma_f32_16x16x32_bf16(vf, pf[kc], O[ob], 0, 0, 0);
            }
    }

    __syncthreads();   // union transition: staging done everywhere
    #pragma unroll
    for (int ob = 0; ob < 4; ob++)
        #pragma unroll
        for (int r = 0; r < 4; r++)
            lds.mg.Osh[wave][l16][ob * 16 + quad * 4 + r] = O[ob][r];
    if (quad == 0) {
        lds.mg.msh[wave][l16] = m;
        lds.mg.lsh[wave][l16] = l;
    }
    __syncthreads();

    // merge key parities: wave pairs (0,2) -> qsub 0, (1,3) -> qsub 1.
    // 32q x 64d = 2048 outputs, 8 per thread.
    #pragma unroll
    for (int part = 0; part < 8; part++) {
        const int idx = part * 256 + tid;
        const int q = idx >> 6;             // 0..31
        const int d = idx & 63;
        const int w0 = (q >> 4), qq = q & 15;   // waves w0 and w0+2
        const float m0 = lds.mg.msh[w0][qq], m1 = lds.mg.msh[w0 + 2][qq];
        const float ms = fmaxf(m0, m1);
        const float x0 = __expf(m0 - ms), x1 = __expf(m1 - ms);
        const float lt = lds.mg.lsh[w0][qq] * x0 + lds.mg.lsh[w0 + 2][qq] * x1;
        const float oa = lds.mg.Osh[w0][qq][d] * x0 + lds.mg.Osh[w0 + 2][qq][d] * x1;
        out[((size_t)b * S_ + qt * 32 + q) * 64 + d] = oa / lt;
    }
}

extern "C" void kernel_launch(void* const* d_in, const int* in_sizes, int n_in,
                              void* d_out, int out_size, void* d_ws, size_t ws_size,
                              hipStream_t stream) {
    const float* x  = (const float*)d_in[0];
    const float* Wq = (const float*)d_in[1];
    const float* bq = (const float*)d_in[2];
    const float* Wk = (const float*)d_in[3];
    const float* bk = (const float*)d_in[4];
    const float* Wv = (const float*)d_in[5];
    const float* bv = (const float*)d_in[6];
    const void* mask = d_in[7];

    char* ws = (char*)d_ws;
    const size_t PLANE = (size_t)B_ * S_ * D_;           // 1M shorts = 2MB
    short* Wpk = (short*)ws;                              // 768 KB
    short* Qhi = (short*)(ws + 768 * 1024);
    short* Qlo = Qhi + PLANE;
    short* Khi = Qlo + PLANE;
    short* Vt  = Khi + PLANE;                             // 512*2112 shorts
    float* maskf = (float*)(Vt + (size_t)512 * VT_STRIDE);

    prep_kernel<<<160, 256, 0, stream>>>(Wq, Wk, Wv, (short8*)Wpk, mask, maskf);
    qkv_kernel<<<512, 512, 0, stream>>>(x, (const short8*)Wpk, bq, bk, bv,
                                        Qhi, Qlo, Khi, Vt);
    attn_kernel<<<512, 256, 0, stream>>>(Qhi, Qlo, Khi, Vt, maskf,
                                         (float*)d_out);
}

// Round 11
// 154.839 us; speedup vs baseline: 1.2134x; 1.0856x over previous
//
#include <hip/hip_runtime.h>
#include <hip/hip_bf16.h>

#define B_ 8
#define S_ 2048
#define E_ 1024
#define D_ 64
#define VT_STRIDE 2112   // 2048 + 64: breaks 4KB channel camping

typedef short short8 __attribute__((ext_vector_type(8)));
typedef short short4v __attribute__((ext_vector_type(4)));
typedef float floatx4 __attribute__((ext_vector_type(4)));

static __device__ __forceinline__ short bf16_bits(float f) {
    __hip_bfloat16 h = __float2bfloat16(f);
    return *reinterpret_cast<short*>(&h);
}
static __device__ __forceinline__ float bits_to_f(short s) {
    __hip_bfloat16 h = *reinterpret_cast<__hip_bfloat16*>(&s);
    return __bfloat162float(h);
}
static __device__ __forceinline__ void split8(const float* __restrict__ p,
                                              short8& hi, short8& lo) {
    #pragma unroll
    for (int j = 0; j < 8; j++) {
        float f = p[j];
        short h = bf16_bits(f);
        hi[j] = h;
        lo[j] = bf16_bits(f - bits_to_f(h));
    }
}
static __device__ __forceinline__ void split8v(const float v[8],
                                               short8& hi, short8& lo) {
    #pragma unroll
    for (int j = 0; j < 8; j++) {
        float f = v[j];
        short h = bf16_bits(f);
        hi[j] = h;
        lo[j] = bf16_bits(f - bits_to_f(h));
    }
}
static __device__ __forceinline__ void dma16(const void* src, void* lds_dst) {
    __builtin_amdgcn_global_load_lds(
        (const __attribute__((address_space(1))) unsigned int*)src,
        (__attribute__((address_space(3))) unsigned int*)lds_dst, 16, 0, 0);
}

// ---------------- prep: blocks 0..95 = W pre-pack (hi only), 96..159 = mask.
// Wpk layout (short8 units): e0c*768 + m*256 + nb*64 + quad*16 + l16
// -> per-e0c 12KB chunk is DMA-linear; reads lane-contiguous b128.
__global__ __launch_bounds__(256) void prep_kernel(
    const float* __restrict__ Wq, const float* __restrict__ Wk,
    const float* __restrict__ Wv, short8* __restrict__ Wpk8,
    const void* __restrict__ mask_raw, float* __restrict__ maskf)
{
    __shared__ unsigned int red[256];
    if (blockIdx.x < 96) {
        const int t = blockIdx.x * 256 + threadIdx.x;       // 24576 total
        const int l16  = t & 15;
        const int quad = (t >> 4) & 3;
        const int nb   = (t >> 6) & 3;
        const int m    = (t >> 8) % 3;
        const int e0c  = (t >> 8) / 3;                      // 0..31
        const float* W = (m == 0) ? Wq : ((m == 1) ? Wk : Wv);
        short8 hi, lo;
        split8(W + (size_t)(nb * 16 + l16) * E_ + e0c * 32 + quad * 8, hi, lo);
        Wpk8[(size_t)e0c * 768 + m * 256 + nb * 64 + quad * 16 + l16] = hi;
    } else {
        const unsigned int* w = (const unsigned int*)mask_raw;
        unsigned int local = 0;
        for (int i = threadIdx.x; i < 4096; i += 256) local |= w[i];
        red[threadIdx.x] = local;
        __syncthreads();
        for (int s = 128; s > 0; s >>= 1) {
            if (threadIdx.x < s) red[threadIdx.x] |= red[threadIdx.x + s];
            __syncthreads();
        }
        const unsigned int ov = red[0];
        const bool is_u8 = (ov > 1u) && ((ov >> 24) <= 1u);
        const int i = (blockIdx.x - 96) * 256 + threadIdx.x;  // 64 blocks
        int v;
        if (ov == 0u)      v = 0;
        else if (is_u8)    v = (int)((const unsigned char*)mask_raw)[i];
        else               v = (((const unsigned int*)mask_raw)[i] != 0u);
        maskf[i] = v ? -1e30f : 0.0f;
    }
}

// ---------------- QKV: 32 rows/block, 512 thr (8 waves = 4 nb x 2 rt),
// grid 512. W single-bf16 (hi), x hi/lo-exact. TWO e0c per barrier round
// (16 rounds): per round every thread issues 3 W-DMA + 1 x-DMA.
__global__ __launch_bounds__(512, 4) void qkv_kernel(
    const float* __restrict__ x, const short8* __restrict__ Wpk8,
    const float* __restrict__ bq, const float* __restrict__ bk,
    const float* __restrict__ bv,
    short* __restrict__ Qhi, short* __restrict__ Qlo,
    short* __restrict__ Khi, short* __restrict__ Vt)
{
    __shared__ alignas(16) float  xs[2][2][1024];   // [buf][c][row*32+col] 16KB
    __shared__ alignas(16) short8 wt[2][1536];      // [buf][c*768+m*256+nb*64+lane] 48KB
    const int tid  = threadIdx.x;
    const int wave = tid >> 6;
    const int nb   = wave & 3;
    const int rt   = wave >> 2;
    const int lane = tid & 63;
    const int l16  = lane & 15;
    const int quad = lane >> 4;
    const int row0 = blockIdx.x * 32;

    // x DMA: thread t -> pair-chunk c=t>>8, row r=(t>>3)&31, sub=t&7.
    // Stored sub holds source col-group sub^(r&7) (read-side swizzle inverse).
    const int xr_  = (tid >> 3) & 31;
    const int xc_  = tid >> 8;
    const float* xsrc = x + (size_t)(row0 + xr_) * E_ + xc_ * 32 +
                        (((tid & 7) ^ (xr_ & 7)) * 4);
    const int xdst = xc_ * 1024 + xr_ * 32 + (tid & 7) * 4;

    floatx4 acc[3];
    #pragma unroll
    for (int m = 0; m < 3; m++) acc[m] = (floatx4){0.f,0.f,0.f,0.f};

    // prime round 0 (e0c pair {0,1})
    #pragma unroll
    for (int i = 0; i < 3; i++)
        dma16(Wpk8 + (size_t)i * 512 + tid, &wt[0][i * 512 + tid]);
    dma16(xsrc, &xs[0][0][0] + xdst);

    int buf = 0;
    for (int R = 0; R < 16; ++R) {
        __syncthreads();   // drains this round's DMA
        if (R + 1 < 16) {
            #pragma unroll
            for (int i = 0; i < 3; i++)
                dma16(Wpk8 + (size_t)(R + 1) * 1536 + i * 512 + tid,
                      &wt[buf ^ 1][i * 512 + tid]);
            dma16(xsrc + (R + 1) * 64, &xs[buf ^ 1][0][0] + xdst);
        }

        #pragma unroll
        for (int c = 0; c < 2; c++) {
            const int rr = rt * 16 + l16;
            const int rx = rr & 7;
            const float* xrp = &xs[buf][c][rr * 32];
            float4 a0 = *reinterpret_cast<const float4*>(xrp + (((2 * quad)     ^ rx) * 4));
            float4 a1 = *reinterpret_cast<const float4*>(xrp + (((2 * quad + 1) ^ rx) * 4));
            float av[8] = {a0.x, a0.y, a0.z, a0.w, a1.x, a1.y, a1.z, a1.w};
            short8 ah, al;
            split8v(av, ah, al);
            #pragma unroll
            for (int m = 0; m < 3; m++) {
                short8 wh = wt[buf][c * 768 + m * 256 + nb * 64 + lane];
                acc[m] = __builtin_amdgcn_mfma_f32_16x16x32_bf16(al, wh, acc[m], 0, 0, 0);
                acc[m] = __builtin_amdgcn_mfma_f32_16x16x32_bf16(ah, wh, acc[m], 0, 0, 0);
            }
        }
        buf ^= 1;
    }

    const int d = nb * 16 + l16;
    const float bqv = bq[d];
    const float bkv = bk[d];
    const float bvv = bv[d];
    const int bch = row0 >> 11;
    const int rowbase = row0 + rt * 16 + quad * 4;
    short4v vpk;
    #pragma unroll
    for (int r = 0; r < 4; r++) {
        const size_t row = (size_t)(rowbase + r);
        const float q = (acc[0][r] + bqv) * 0.125f;
        const short qhv = bf16_bits(q);
        Qhi[row * 64 + d] = qhv;
        Qlo[row * 64 + d] = bf16_bits(q - bits_to_f(qhv));
        Khi[row * 64 + d] = bf16_bits(acc[1][r] + bkv);
        vpk[r] = bf16_bits(acc[2][r] + bvv);
    }
    *reinterpret_cast<short4v*>(Vt + ((size_t)(bch * 64 + d)) * VT_STRIDE +
                                (rowbase & 2047)) = vpk;
}

// ---------------- Flash attention (unchanged from round 10): 32 q/block,
// grid 512, pair-staged K/V tiles, key-parity waves, in-block LSE merge.
union alignas(16) AttnLds {
    struct { short8 kts[4][512]; short8 vts[4][512]; } st;  // 64KB
    struct {
        float Osh[4][16][65];
        float msh[4][16], lsh[4][16];
    } mg;
};

__global__ __launch_bounds__(256, 2) void attn_kernel(
    const short* __restrict__ Qhi, const short* __restrict__ Qlo,
    const short* __restrict__ Khi, const short* __restrict__ Vt,
    const float* __restrict__ maskf, float* __restrict__ out)
{
    __shared__ AttnLds lds;
    __shared__ short PlT[4][16][72];

    const int tid  = threadIdx.x;
    const int wave = tid >> 6;
    const int qsub = wave & 1;
    const int par  = wave >> 1;
    const int lane = tid & 63;
    const int l16  = lane & 15;
    const int quad = lane >> 4;
    const int b    = blockIdx.x >> 6;
    const int qt   = blockIdx.x & 63;
    const size_t qbase  = (size_t)b * S_ + qt * 32 + qsub * 16;
    const size_t kplane = (size_t)b * S_;
    const short* Vb = Vt + (size_t)b * 64 * VT_STRIDE;

    short8 qh[2], ql[2];
    #pragma unroll
    for (int dc = 0; dc < 2; dc++) {
        qh[dc] = *reinterpret_cast<const short8*>(Qhi + (qbase + l16) * 64 + dc * 32 + quad * 8);
        ql[dc] = *reinterpret_cast<const short8*>(Qlo + (qbase + l16) * 64 + dc * 32 + quad * 8);
    }

    float m = -1e30f, l = 0.f;
    floatx4 O[4];
    #pragma unroll
    for (int ob = 0; ob < 4; ob++) O[ob] = (floatx4){0.f,0.f,0.f,0.f};

    #pragma unroll
    for (int p = 0; p < 2; p++) {
        #pragma unroll
        for (int i = 0; i < 2; i++) {
            const int c = i * 256 + tid;
            const int r = c >> 3, cs = c & 7;
            dma16(Khi + (kplane + p * 64 + r) * 64 + ((cs ^ (r & 7)) * 8),
                  &lds.st.kts[p][c]);
            dma16(Vb + (size_t)r * VT_STRIDE + p * 64 + ((cs ^ (r & 7)) * 8),
                  &lds.st.vts[p][c]);
        }
    }
    float4 mk4[4];
    #pragma unroll
    for (int kb = 0; kb < 4; kb++)
        mk4[kb] = *reinterpret_cast<const float4*>(
            maskf + kplane + par * 64 + kb * 16 + quad * 4);

    for (int R = 0; R < 16; ++R) {
        __syncthreads();
        const int set = R & 1;
        if (R + 1 < 16) {
            const int nset = set ^ 1;
            const int kt2 = (R + 1) * 128;
            #pragma unroll
            for (int p = 0; p < 2; p++) {
                #pragma unroll
                for (int i = 0; i < 2; i++) {
                    const int c = i * 256 + tid;
                    const int r = c >> 3, cs = c & 7;
                    dma16(Khi + (kplane + kt2 + p * 64 + r) * 64 + ((cs ^ (r & 7)) * 8),
                          &lds.st.kts[nset * 2 + p][c]);
                    dma16(Vb + (size_t)r * VT_STRIDE + kt2 + p * 64 + ((cs ^ (r & 7)) * 8),
                          &lds.st.vts[nset * 2 + p][c]);
                }
            }
        }
        const int buf = set * 2 + par;

        floatx4 sc[4];
        #pragma unroll
        for (int kb = 0; kb < 4; kb++) {
            floatx4 a = (floatx4){0.f,0.f,0.f,0.f};
            #pragma unroll
            for (int kc = 0; kc < 2; kc++) {
                const int key = kb * 16 + l16;
                short8 kf = lds.st.kts[buf][key * 8 + ((kc * 4 + quad) ^ (key & 7))];
                a = __builtin_amdgcn_mfma_f32_16x16x32_bf16(kf, qh[kc], a, 0, 0, 0);
                a = __builtin_amdgcn_mfma_f32_16x16x32_bf16(kf, ql[kc], a, 0, 0, 0);
            }
            sc[kb] = a;
        }
        #pragma unroll
        for (int kb = 0; kb < 4; kb++) {
            const float* mkp = reinterpret_cast<const float*>(&mk4[kb]);
            #pragma unroll
            for (int r = 0; r < 4; r++) sc[kb][r] += mkp[r];
        }

        if (R + 1 < 16) {
            const int ktn = (R + 1) * 128 + par * 64;
            #pragma unroll
            for (int kb = 0; kb < 4; kb++)
                mk4[kb] = *reinterpret_cast<const float4*>(
                    maskf + kplane + ktn + kb * 16 + quad * 4);
        }

        float mx = -1e30f;
        #pragma unroll
        for (int kb = 0; kb < 4; kb++)
            #pragma unroll
            for (int r = 0; r < 4; r++) mx = fmaxf(mx, sc[kb][r]);
        mx = fmaxf(mx, __shfl_xor(mx, 16, 64));
        mx = fmaxf(mx, __shfl_xor(mx, 32, 64));
        const float mnew  = fmaxf(fmaxf(m, mx), -1e29f);
        const float alpha = __expf(m - mnew);
        float ps = 0.f;
        #pragma unroll
        for (int kb = 0; kb < 4; kb++)
            #pragma unroll
            for (int r = 0; r < 4; r++) {
                const float pe = __expf(sc[kb][r] - mnew);
                sc[kb][r] = pe;
                ps += pe;
            }
        ps += __shfl_xor(ps, 16, 64);
        ps += __shfl_xor(ps, 32, 64);
        l = l * alpha + ps;
        m = mnew;
        #pragma unroll
        for (int ob = 0; ob < 4; ob++) O[ob] *= alpha;

        #pragma unroll
        for (int kb = 0; kb < 4; kb++)
            #pragma unroll
            for (int r = 0; r < 4; r++)
                PlT[wave][l16][kb * 16 + quad * 4 + r] = bf16_bits(sc[kb][r]);
        short8 pf[2];
        #pragma unroll
        for (int kc = 0; kc < 2; kc++)
            pf[kc] = *reinterpret_cast<const short8*>(&PlT[wave][l16][kc * 32 + quad * 8]);

        #pragma unroll
        for (int ob = 0; ob < 4; ob++)
            #pragma unroll
            for (int kc = 0; kc < 2; kc++) {
                const int dd = ob * 16 + l16;
                short8 vf = lds.st.vts[buf][dd * 8 + ((kc * 4 + quad) ^ (dd & 7))];
                O[ob] = __builtin_amdgcn_mfma_f32_16x16x32_bf16(vf, pf[kc], O[ob], 0, 0, 0);
            }
    }

    __syncthreads();
    #pragma unroll
    for (int ob = 0; ob < 4; ob++)
        #pragma unroll
        for (int r = 0; r < 4; r++)
            lds.mg.Osh[wave][l16][ob * 16 + quad * 4 + r] = O[ob][r];
    if (quad == 0) {
        lds.mg.msh[wave][l16] = m;
        lds.mg.lsh[wave][l16] = l;
    }
    __syncthreads();

    #pragma unroll
    for (int part = 0; part < 8; part++) {
        const int idx = part * 256 + tid;
        const int q = idx >> 6;
        const int d = idx & 63;
        const int w0 = (q >> 4), qq = q & 15;
        const float m0 = lds.mg.msh[w0][qq], m1 = lds.mg.msh[w0 + 2][qq];
        const float ms = fmaxf(m0, m1);
        const float x0 = __expf(m0 - ms), x1 = __expf(m1 - ms);
        const float lt = lds.mg.lsh[w0][qq] * x0 + lds.mg.lsh[w0 + 2][qq] * x1;
        const float oa = lds.mg.Osh[w0][qq][d] * x0 + lds.mg.Osh[w0 + 2][qq][d] * x1;
        out[((size_t)b * S_ + qt * 32 + q) * 64 + d] = oa / lt;
    }
}

extern "C" void kernel_launch(void* const* d_in, const int* in_sizes, int n_in,
                              void* d_out, int out_size, void* d_ws, size_t ws_size,
                              hipStream_t stream) {
    const float* x  = (const float*)d_in[0];
    const float* Wq = (const float*)d_in[1];
    const float* bq = (const float*)d_in[2];
    const float* Wk = (const float*)d_in[3];
    const float* bk = (const float*)d_in[4];
    const float* Wv = (const float*)d_in[5];
    const float* bv = (const float*)d_in[6];
    const void* mask = d_in[7];

    char* ws = (char*)d_ws;
    const size_t PLANE = (size_t)B_ * S_ * D_;           // 1M shorts = 2MB
    short* Wpk = (short*)ws;                              // 384 KB used (768 reserved)
    short* Qhi = (short*)(ws + 768 * 1024);
    short* Qlo = Qhi + PLANE;
    short* Khi = Qlo + PLANE;
    short* Vt  = Khi + PLANE;                             // 512*2112 shorts
    float* maskf = (float*)(Vt + (size_t)512 * VT_STRIDE);

    prep_kernel<<<160, 256, 0, stream>>>(Wq, Wk, Wv, (short8*)Wpk, mask, maskf);
    qkv_kernel<<<512, 512, 0, stream>>>(x, (const short8*)Wpk, bq, bk, bv,
                                        Qhi, Qlo, Khi, Vt);
    attn_kernel<<<512, 256, 0, stream>>>(Qhi, Qlo, Khi, Vt, maskf,
                                         (float*)d_out);
}